// Round 1
// baseline (667.438 us; speedup 1.0000x reference)
//
#include <hip/hip_runtime.h>
#include <math.h>

#define BATCH   4096
#define NPTS    8192
#define BCHUNK  32
#define TPB     256
// Each thread handles 4 consecutive n -> 12 contiguous output floats per row
// Block covers 1024 n; grid = (NPTS/1024, BATCH/BCHUNK) = (8, 128)

__device__ __forceinline__ float softplus_f(float x) {
    // stable: max(x,0) + log1p(exp(-|x|))
    return fmaxf(x, 0.0f) + log1pf(__expf(-fabsf(x)) * 0.0f + expf(-fabsf(x)));
}

__global__ __launch_bounds__(TPB) void block_layer_kernel(
    const float* __restrict__ inp,   // (BATCH, 3)
    const float* __restrict__ wgt,   // (NPTS, 6)
    float* __restrict__ out)         // (BATCH, NPTS*3)
{
    const int t = threadIdx.x;
    const int nChunk = blockIdx.x;      // 0..7
    const int bChunk = blockIdx.y;      // 0..127
    const int g  = nChunk * TPB + t;    // n-group id (4 n's per group)
    const int n0 = g * 4;

    // Load weight rows n0..n0+3: 24 floats = 96 B contiguous, float4-aligned
    const float4* wv = reinterpret_cast<const float4*>(wgt + (size_t)n0 * 6);
    float4 w[6];
    #pragma unroll
    for (int i = 0; i < 6; ++i) w[i] = wv[i];
    const float* wf = reinterpret_cast<const float*>(w);

    // Build B = M^T M for 4 n's (symmetric: 6 unique entries each)
    float B00[4], B01[4], B02[4], B11[4], B12[4], B22[4];
    #pragma unroll
    for (int i = 0; i < 4; ++i) {
        float w0 = wf[i*6+0], w1 = wf[i*6+1], w2 = wf[i*6+2];
        float w3 = wf[i*6+3], w4 = wf[i*6+4], w5 = wf[i*6+5];
        float a = fmaxf(w0, 0.0f) + log1pf(expf(-fabsf(w0)));
        float d = fmaxf(w3, 0.0f) + log1pf(expf(-fabsf(w3)));
        float f = fmaxf(w5, 0.0f) + log1pf(expf(-fabsf(w5)));
        B00[i] = a*a;
        B01[i] = a*w1;
        B02[i] = a*w2;
        B11[i] = w1*w1 + d*d;
        B12[i] = w1*w2 + d*w4;
        B22[i] = w2*w2 + w4*w4 + f*f;
    }

    const int bBase = bChunk * BCHUNK;
    const size_t rowStride = (size_t)NPTS * 3;
    const size_t colOff = (size_t)n0 * 3;   // divisible by 4 -> float4 aligned

    #pragma unroll 4
    for (int bi = 0; bi < BCHUNK; ++bi) {
        const int b = bBase + bi;
        const float x = inp[b*3 + 0];
        const float y = inp[b*3 + 1];
        const float z = inp[b*3 + 2];
        float o[12];
        #pragma unroll
        for (int i = 0; i < 4; ++i) {
            o[i*3+0] = x*B00[i] + y*B01[i] + z*B02[i];
            o[i*3+1] = x*B01[i] + y*B11[i] + z*B12[i];
            o[i*3+2] = x*B02[i] + y*B12[i] + z*B22[i];
        }
        float4* dst = reinterpret_cast<float4*>(out + (size_t)b * rowStride + colOff);
        dst[0] = make_float4(o[0], o[1], o[2],  o[3]);
        dst[1] = make_float4(o[4], o[5], o[6],  o[7]);
        dst[2] = make_float4(o[8], o[9], o[10], o[11]);
    }
}

extern "C" void kernel_launch(void* const* d_in, const int* in_sizes, int n_in,
                              void* d_out, int out_size, void* d_ws, size_t ws_size,
                              hipStream_t stream) {
    const float* inp = (const float*)d_in[0];   // (4096, 3)
    const float* wgt = (const float*)d_in[1];   // (8192, 6)
    float* out = (float*)d_out;                 // (4096, 24576)

    dim3 grid(NPTS / (TPB * 4), BATCH / BCHUNK);  // (8, 128)
    dim3 block(TPB);
    hipLaunchKernelGGL(block_layer_kernel, grid, block, 0, stream, inp, wgt, out);
}